// Round 1
// baseline (417.682 us; speedup 1.0000x reference)
//
#include <hip/hip_runtime.h>

#define NEG_INF (-1e9f)
#define SCALE_F 0.08838834764831845f

typedef __attribute__((ext_vector_type(8))) short short8;
typedef __attribute__((ext_vector_type(4))) float float4v;

__device__ __constant__ int cDR[8] = {1,1,0,-1,-1,-1,0,1};
__device__ __constant__ int cDC[8] = {0,1,1,1,0,-1,-1,-1};
__device__ __constant__ int cKR[8] = {2,1,-1,-2,-2,-1,1,2};
__device__ __constant__ int cKC[8] = {1,2,2,1,-1,-2,-2,-1};

__device__ __forceinline__ ushort f2bf(float f) {
  union { float f; unsigned u; } a; a.f = f;
  unsigned u = a.u;
  return (ushort)((u + 0x7FFFu + ((u >> 16) & 1u)) >> 16);
}

// async 16B/lane copy: global -> LDS. ldsbase must be wave-uniform; lane i
// receives bytes [i*16, i*16+16).
__device__ __forceinline__ void glds16(const void* g, void* l) {
  __builtin_amdgcn_global_load_lds(
      (const __attribute__((address_space(1))) unsigned int*)g,
      (__attribute__((address_space(3))) unsigned int*)l, 16, 0, 0);
}

// truncation-pack 8 f32 -> 8 bf16 (error 2^-8, irrelevant vs threshold)
__device__ __forceinline__ short8 pack8(float4 a, float4 b) {
  union { short8 v; unsigned u[4]; } o;
  unsigned a0 = __float_as_uint(a.x), a1 = __float_as_uint(a.y);
  unsigned a2 = __float_as_uint(a.z), a3 = __float_as_uint(a.w);
  unsigned b0 = __float_as_uint(b.x), b1 = __float_as_uint(b.y);
  unsigned b2 = __float_as_uint(b.z), b3 = __float_as_uint(b.w);
  o.u[0] = (a1 & 0xFFFF0000u) | (a0 >> 16);
  o.u[1] = (a3 & 0xFFFF0000u) | (a2 >> 16);
  o.u[2] = (b1 & 0xFFFF0000u) | (b0 >> 16);
  o.u[3] = (b3 & 0xFFFF0000u) | (b2 >> 16);
  return o.v;
}

// Wsw layout: [kc][row][sseg*8+j] bf16, chunk-major (18432 elems/chunk),
// row 0..287: 0-127 Wq cols, 128-255 Wk cols, 256-264 Wu cols, 265-287 zero.
// XOR swizzle: position sseg holds original k-seg (sseg ^ (row&7)); 16B
// granules stay contiguous so global_load_lds copies are linear.
__global__ void wconv_kernel(const float* __restrict__ Wq,
                             const float* __restrict__ Wk,
                             const float* __restrict__ Wu,
                             ushort* __restrict__ Wsw) {
  int row = blockIdx.x;  // 0..287
  for (int k = threadIdx.x; k < 1024; k += 256) {
    float v;
    if (row < 128)      v = Wq[k * 128 + row];
    else if (row < 256) v = Wk[k * 128 + (row - 128)];
    else if (row < 265) v = Wu[k * 9 + (row - 256)];
    else                v = 0.f;
    int kc = k >> 6, kin = k & 63, seg = kin >> 3, j = kin & 7;
    int sseg = seg ^ (row & 7);
    Wsw[(size_t)kc * 18432 + row * 64 + sseg * 8 + j] = f2bf(v);
  }
}

// 2 batch elements per block: M=128 rows (rows 0-63 elem0, 64-127 elem1).
// 512 blocks, 2 blocks/CU co-resident (one dispatch round, no tail);
// halves per-element W staging + barrier count vs 1-elem/block.
__global__ __launch_bounds__(256, 2)
void apol_main(const float* __restrict__ x,
               const float* __restrict__ bq,
               const float* __restrict__ bk,
               const float* __restrict__ bu,
               const ushort* __restrict__ Wsw,
               float* __restrict__ out) {
  // LDS union:
  //  phase1: xs f32[2][64][64] (32768 B) + wt bf16[288][64] (36864 B) = 69632 B
  //  phase2: qs[2][64][132] + ks[2][64][132] bf16                     = 67584 B
  //  phase3: Sl f32[2][64][65]                                        = 33280 B
  __shared__ __align__(16) char smem[69632];
  char*   xsB = smem;            // f32 x tile (2 elems), XOR-swizzled granules
  char*   wtB = smem + 32768;    // bf16 W tile (copied pre-swizzled)
  ushort* qs  = (ushort*)smem;                 // [2][64][132]
  ushort* ks  = (ushort*)(smem + 33792);       // [2][64][132]
  float*  Sl  = (float*)smem;                  // [2][64][65]

  const int tid = threadIdx.x;
  const int w = tid >> 6, lane = tid & 63;
  const int l15 = lane & 15, qd = lane >> 4;
  const char* xb = (const char*)(x + (size_t)blockIdx.x * 131072);  // 2 elems
  const char* WsB = (const char*)Wsw;

  // x staging source offsets: 8 calls/wave, 1KB each; 32 KB/chunk total.
  int xsrc[8];
  #pragma unroll
  for (int c = 0; c < 8; ++c) {
    int g = (c * 4 + w) * 64 + lane;   // granule 0..2047
    int e = g >> 10, gg = g & 1023;
    int row = gg >> 4, sg = gg & 15;
    xsrc[c] = e * 262144 + row * 4096 + ((sg ^ (row & 7)) * 16);
  }

  // A-fragment LDS byte addr: mt*4096 + l15*256 + xoff[kk][h]
  // (elem stride 16384 = 4*4096 makes the mt term uniform across elems;
  //  row&7 == l15&7 since row = 16*m + l15)
  int xoff[2][2];
  #pragma unroll
  for (int kk = 0; kk < 2; ++kk)
    #pragma unroll
    for (int h = 0; h < 2; ++h)
      xoff[kk][h] = (((kk * 8 + qd * 2 + h) ^ (l15 & 7)) * 16);
  const int arow = l15 * 256;

  // B-fragment LDS byte addrs: row=w*64+nt*16+l15, k-seg kk*4+qd, swizzled.
  int baddr[4][2], uaddr[2];
  #pragma unroll
  for (int nt = 0; nt < 4; ++nt) {
    int row = w * 64 + nt * 16 + l15;
    #pragma unroll
    for (int kk = 0; kk < 2; ++kk)
      baddr[nt][kk] = row * 128 + (((kk * 4 + qd) ^ (l15 & 7)) * 16);
  }
  #pragma unroll
  for (int kk = 0; kk < 2; ++kk)
    uaddr[kk] = (256 + l15) * 128 + (((kk * 4 + qd) ^ (l15 & 7)) * 16);

  float4v acc[8][4];
  #pragma unroll
  for (int i = 0; i < 8; ++i)
    #pragma unroll
    for (int j = 0; j < 4; ++j)
      acc[i][j] = (float4v){0.f, 0.f, 0.f, 0.f};
  float4v aup[2];
  aup[0] = (float4v){0.f, 0.f, 0.f, 0.f};
  aup[1] = (float4v){0.f, 0.f, 0.f, 0.f};

  // ---------------- GEMM1: 16 chunks of BK=64 ----------------
  #pragma unroll 1
  for (int kc = 0; kc < 16; ++kc) {
    // issue async staging: x 32KB (8 calls) + W 36KB (9 calls)
    #pragma unroll
    for (int c = 0; c < 8; ++c)
      glds16(xb + kc * 256 + xsrc[c], xsB + (c * 4 + w) * 1024);
    const char* wsrc = WsB + (size_t)kc * 36864 + (size_t)lane * 16;
    #pragma unroll
    for (int c = 0; c < 9; ++c)
      glds16(wsrc + (c * 4 + w) * 1024, wtB + (c * 4 + w) * 1024);
    __syncthreads();

    #pragma unroll
    for (int kk = 0; kk < 2; ++kk) {
      short8 bf[4];
      #pragma unroll
      for (int nt = 0; nt < 4; ++nt)
        bf[nt] = *(const short8*)(wtB + baddr[nt][kk]);
      short8 ub;
      if (w == 3) ub = *(const short8*)(wtB + uaddr[kk]);
      #pragma unroll
      for (int mt = 0; mt < 8; ++mt) {
        float4 g0 = *(const float4*)(xsB + mt * 4096 + arow + xoff[kk][0]);
        float4 g1 = *(const float4*)(xsB + mt * 4096 + arow + xoff[kk][1]);
        short8 af = pack8(g0, g1);
        #pragma unroll
        for (int nt = 0; nt < 4; ++nt)
          acc[mt][nt] = __builtin_amdgcn_mfma_f32_16x16x32_bf16(
              af, bf[nt], acc[mt][nt], 0, 0, 0);
        if (w == 3 && (mt & 3) == 3)  // promo cols, elem = mt>>2
          aup[mt >> 2] = __builtin_amdgcn_mfma_f32_16x16x32_bf16(
              af, ub, aup[mt >> 2], 0, 0, 0);
      }
    }
    __syncthreads();
  }

  // promo writes: wave 3, C rows 0..7 <-> x rows 48..55 of each elem, cols 0..8
  if (w == 3 && qd < 2 && l15 < 9) {
    float bias = bu[l15];
    #pragma unroll
    for (int e = 0; e < 2; ++e) {
      float* oe = out + (size_t)(blockIdx.x * 2 + e) * 4672;
      #pragma unroll
      for (int r = 0; r < 4; ++r) {
        int f = 48 + qd * 4 + r;
        oe[f * 73 + 64 + l15] = aup[e][r] + bias;
      }
    }
  }

  // ---------------- epilogue: acc -> qs/ks (bias, scale) ----------------
  #pragma unroll
  for (int nt = 0; nt < 4; ++nt) {
    int C = w * 64 + nt * 16 + l15;
    bool isq = (C < 128);
    int p = isq ? C : (C - 128);
    float bias = isq ? bq[p] : bk[p];
    ushort* dstb = isq ? qs : ks;
    #pragma unroll
    for (int mt = 0; mt < 8; ++mt)
      #pragma unroll
      for (int r = 0; r < 4; ++r) {
        int row = mt * 16 + qd * 4 + r;   // 0..127
        int e = row >> 6, sr = row & 63;
        float v = acc[mt][nt][r] + bias;
        if (isq) v *= SCALE_F;
        dstb[e * 8448 + sr * 132 + p] = f2bf(v);
      }
  }
  __syncthreads();

  // ---------------- GEMM2: S = q' @ k'^T (64x64 per elem), K=128 ----------
  float4v acc2[2][4];
  #pragma unroll
  for (int e = 0; e < 2; ++e)
    #pragma unroll
    for (int nt = 0; nt < 4; ++nt) acc2[e][nt] = (float4v){0.f, 0.f, 0.f, 0.f};
  #pragma unroll
  for (int e = 0; e < 2; ++e)
    #pragma unroll
    for (int kp = 0; kp < 4; ++kp) {
      int kb = kp * 32 + qd * 8;
      short8 a2 = *(const short8*)((const char*)&qs[e * 8448 + (w * 16 + l15) * 132 + kb]);
      #pragma unroll
      for (int nt = 0; nt < 4; ++nt) {
        short8 b2 = *(const short8*)((const char*)&ks[e * 8448 + (nt * 16 + l15) * 132 + kb]);
        acc2[e][nt] = __builtin_amdgcn_mfma_f32_16x16x32_bf16(a2, b2, acc2[e][nt], 0, 0, 0);
      }
    }
  __syncthreads();
  #pragma unroll
  for (int e = 0; e < 2; ++e)
    #pragma unroll
    for (int nt = 0; nt < 4; ++nt)
      #pragma unroll
      for (int r = 0; r < 4; ++r)
        Sl[e * 4160 + (w * 16 + qd * 4 + r) * 65 + nt * 16 + l15] = acc2[e][nt][r];
  __syncthreads();

  // ---------------- gather + masks + store ----------------
  #pragma unroll 1
  for (int e = 0; e < 2; ++e) {
    float* oe = out + (size_t)(blockIdx.x * 2 + e) * 4672;
    const float* Se = Sl + e * 4160;
    for (int idx = tid; idx < 4672; idx += 256) {
      int f = idx / 73;
      int j = idx - f * 73;
      float val;
      if (j < 64) {
        int rr = f >> 3, cc = f & 7;
        int nr, nc;
        if (j < 56) {
          int d = j / 7;
          int dist = j - d * 7 + 1;
          nr = rr + cDR[d] * dist;
          nc = cc + cDC[d] * dist;
        } else {
          nr = rr + cKR[j - 56];
          nc = cc + cKC[j - 56];
        }
        val = (nr >= 0 && nr < 8 && nc >= 0 && nc < 8) ? Se[f * 65 + nr * 8 + nc]
                                                       : NEG_INF;
      } else {
        if (f >= 48 && f < 56) continue;  // promo rows written from aup
        val = NEG_INF;
      }
      oe[idx] = val;
    }
  }
}

extern "C" void kernel_launch(void* const* d_in, const int* in_sizes, int n_in,
                              void* d_out, int out_size, void* d_ws, size_t ws_size,
                              hipStream_t stream) {
  const float* x  = (const float*)d_in[0];
  const float* Wq = (const float*)d_in[1];
  const float* bq = (const float*)d_in[2];
  const float* Wk = (const float*)d_in[3];
  const float* bk = (const float*)d_in[4];
  const float* Wu = (const float*)d_in[5];
  const float* bu = (const float*)d_in[6];
  float* out = (float*)d_out;
  ushort* Wsw = (ushort*)d_ws;  // 16*18432 bf16 = 576 KB

  const int B = in_sizes[0] / 65536;

  wconv_kernel<<<288, 256, 0, stream>>>(Wq, Wk, Wu, Wsw);
  apol_main<<<B / 2, 256, 0, stream>>>(x, bq, bk, bu, Wsw, out);
}